// Round 1
// baseline (128.979 us; speedup 1.0000x reference)
//
#include <hip/hip_runtime.h>

// 8-qubit statevector sim, one sample per wave64, 4 amps/lane (amp bits 0..1
// in-lane as j, amp bits 2..7 = lane bits). Qubit q <-> amp bit 7-q.
// RX*RY*RZ per (layer,qubit) fused into one 2x2 complex gate in LDS.

#define NQ 8
#define NL 4
#define NGATES 32

__global__ __launch_bounds__(256) void qsim(const float* __restrict__ x,
                                            const float* __restrict__ w,
                                            float* __restrict__ out, int B)
{
    __shared__ float gsh[NGATES][8];  // u00r,u00i,u01r,u01i,u10r,u10i,u11r,u11i

    const int tid = threadIdx.x;
    if (tid < NGATES) {
        float hx = 0.5f * w[tid*3+0];
        float hy = 0.5f * w[tid*3+1];
        float hz = 0.5f * w[tid*3+2];
        float cx = cosf(hx), sx = sinf(hx);
        float cy = cosf(hy), sy = sinf(hy);
        float cz = cosf(hz), sz = sinf(hz);
        // M = RY*RX:
        //  m00 = cy*cx + i sy*sx      m01 = -sy*cx - i cy*sx
        //  m10 = sy*cx - i cy*sx      m11 =  cy*cx - i sy*sx
        float m00r = cy*cx,  m00i =  sy*sx;
        float m01r = -sy*cx, m01i = -cy*sx;
        float m10r = sy*cx,  m10i = -cy*sx;
        float m11r = cy*cx,  m11i = -sy*sx;
        // U = RZ*M: row0 *= (cz - i sz), row1 *= (cz + i sz)
        gsh[tid][0] = cz*m00r + sz*m00i;
        gsh[tid][1] = cz*m00i - sz*m00r;
        gsh[tid][2] = cz*m01r + sz*m01i;
        gsh[tid][3] = cz*m01i - sz*m01r;
        gsh[tid][4] = cz*m10r - sz*m10i;
        gsh[tid][5] = cz*m10i + sz*m10r;
        gsh[tid][6] = cz*m11r - sz*m11i;
        gsh[tid][7] = cz*m11i + sz*m11r;
    }
    __syncthreads();

    const int lane = tid & 63;
    const int wv   = tid >> 6;
    const int sample = blockIdx.x * 4 + wv;
    if (sample >= B) return;

    // ---- encoding: product state amp(i) = prod_q (bit_{7-q}(i) ? sin : cos)(x_q/2)
    const float4* xp = (const float4*)(x + sample * 8);
    float4 xa = xp[0], xb = xp[1];
    float xs[8] = {xa.x, xa.y, xa.z, xa.w, xb.x, xb.y, xb.z, xb.w};
    float cq[8], sq[8];
    #pragma unroll
    for (int q = 0; q < 8; ++q) {
        float h = 0.5f * xs[q];
        __sincosf(h, &sq[q], &cq[q]);
    }
    // lane bit k (0..5) <-> amp bit k+2 <-> qubit 5-k
    float lp = 1.f;
    #pragma unroll
    for (int k = 0; k < 6; ++k)
        lp *= ((lane >> k) & 1) ? sq[5 - k] : cq[5 - k];

    float ar[4], ai[4];
    ar[0] = lp * cq[6] * cq[7];   // j bit1 -> qubit 6, j bit0 -> qubit 7
    ar[1] = lp * cq[6] * sq[7];
    ar[2] = lp * sq[6] * cq[7];
    ar[3] = lp * sq[6] * sq[7];
    ai[0] = ai[1] = ai[2] = ai[3] = 0.f;

    #pragma unroll
    for (int layer = 0; layer < NL; ++layer) {
        // --- fused 1q gates, q=0..5: amp bit b=7-q (cross-lane, lane bit 5-q)
        #pragma unroll
        for (int q = 0; q < 6; ++q) {
            const int g  = layer * 8 + q;
            const int lm = 1 << (5 - q);
            const int sel = (lane >> (5 - q)) & 1;
            // sel=0: new = u00*a + u01*partner ; sel=1: new = u11*a + u10*partner
            float u0r = sel ? gsh[g][6] : gsh[g][0];
            float u0i = sel ? gsh[g][7] : gsh[g][1];
            float u1r = sel ? gsh[g][4] : gsh[g][2];
            float u1i = sel ? gsh[g][5] : gsh[g][3];
            #pragma unroll
            for (int j = 0; j < 4; ++j) {
                float br = __shfl_xor(ar[j], lm);
                float bi = __shfl_xor(ai[j], lm);
                float nr = u0r*ar[j] - u0i*ai[j] + u1r*br - u1i*bi;
                float ni = u0r*ai[j] + u0i*ar[j] + u1r*bi + u1i*br;
                ar[j] = nr; ai[j] = ni;
            }
        }
        // --- q=6: amp bit 1 (local pairs (0,2),(1,3))
        {
            const int g = layer * 8 + 6;
            float u00r=gsh[g][0], u00i=gsh[g][1], u01r=gsh[g][2], u01i=gsh[g][3];
            float u10r=gsh[g][4], u10i=gsh[g][5], u11r=gsh[g][6], u11i=gsh[g][7];
            #pragma unroll
            for (int j0 = 0; j0 < 2; ++j0) {
                const int j1 = j0 + 2;
                float a0r=ar[j0], a0i=ai[j0], a1r=ar[j1], a1i=ai[j1];
                ar[j0] = u00r*a0r - u00i*a0i + u01r*a1r - u01i*a1i;
                ai[j0] = u00r*a0i + u00i*a0r + u01r*a1i + u01i*a1r;
                ar[j1] = u10r*a0r - u10i*a0i + u11r*a1r - u11i*a1i;
                ai[j1] = u10r*a0i + u10i*a0r + u11r*a1i + u11i*a1r;
            }
        }
        // --- q=7: amp bit 0 (local pairs (0,1),(2,3))
        {
            const int g = layer * 8 + 7;
            float u00r=gsh[g][0], u00i=gsh[g][1], u01r=gsh[g][2], u01i=gsh[g][3];
            float u10r=gsh[g][4], u10i=gsh[g][5], u11r=gsh[g][6], u11i=gsh[g][7];
            #pragma unroll
            for (int j0 = 0; j0 < 4; j0 += 2) {
                const int j1 = j0 + 1;
                float a0r=ar[j0], a0i=ai[j0], a1r=ar[j1], a1i=ai[j1];
                ar[j0] = u00r*a0r - u00i*a0i + u01r*a1r - u01i*a1i;
                ai[j0] = u00r*a0i + u00i*a0r + u01r*a1i + u01i*a1r;
                ar[j1] = u10r*a0r - u10i*a0i + u11r*a1r - u11i*a1i;
                ai[j1] = u10r*a0i + u10i*a0r + u11r*a1i + u11i*a1r;
            }
        }
        // --- CNOT chain: (c,t)=(q,q+1) -> (bc,bt)=(7-q,6-q)
        // q=0..4: both bits cross-lane: lc=5-q, lt=4-q
        #pragma unroll
        for (int q = 0; q < 5; ++q) {
            const int lc = 5 - q;
            const int lm = 1 << (4 - q);
            const bool cc = (lane >> lc) & 1;
            #pragma unroll
            for (int j = 0; j < 4; ++j) {
                float tr = __shfl_xor(ar[j], lm);
                float ti = __shfl_xor(ai[j], lm);
                if (cc) { ar[j] = tr; ai[j] = ti; }
            }
        }
        // q=5: control = lane bit0, target = local j bit1: swap (0,2),(1,3)
        {
            const bool cc = lane & 1;
            if (cc) {
                float t;
                t=ar[0]; ar[0]=ar[2]; ar[2]=t;  t=ai[0]; ai[0]=ai[2]; ai[2]=t;
                t=ar[1]; ar[1]=ar[3]; ar[3]=t;  t=ai[1]; ai[1]=ai[3]; ai[3]=t;
            }
        }
        // q=6: control = j bit1, target = j bit0: swap a[2]<->a[3]
        {
            float t;
            t=ar[2]; ar[2]=ar[3]; ar[3]=t;
            t=ai[2]; ai[2]=ai[3]; ai[3]=t;
        }
    }

    // ---- measurement: z_q = sum_i |amp_i|^2 * (-1)^{bit_{7-q}(i)}
    float p0 = ar[0]*ar[0] + ai[0]*ai[0];
    float p1 = ar[1]*ar[1] + ai[1]*ai[1];
    float p2 = ar[2]*ar[2] + ai[2]*ai[2];
    float p3 = ar[3]*ar[3] + ai[3]*ai[3];
    float P  = p0 + p1 + p2 + p3;

    float v[8];
    #pragma unroll
    for (int q = 0; q < 6; ++q)
        v[q] = ((lane >> (5 - q)) & 1) ? -P : P;
    v[6] = p0 + p1 - p2 - p3;   // qubit 6 <-> j bit1
    v[7] = p0 - p1 + p2 - p3;   // qubit 7 <-> j bit0

    #pragma unroll
    for (int m = 1; m < 64; m <<= 1) {
        #pragma unroll
        for (int q = 0; q < 8; ++q)
            v[q] += __shfl_xor(v[q], m);
    }

    if (lane == 0) {
        float4* op = (float4*)(out + sample * 8);
        op[0] = make_float4(v[0], v[1], v[2], v[3]);
        op[1] = make_float4(v[4], v[5], v[6], v[7]);
    }
}

extern "C" void kernel_launch(void* const* d_in, const int* in_sizes, int n_in,
                              void* d_out, int out_size, void* d_ws, size_t ws_size,
                              hipStream_t stream) {
    const float* x = (const float*)d_in[0];
    const float* w = (const float*)d_in[1];
    float* out = (float*)d_out;
    const int B = in_sizes[0] / 8;          // 16384 samples
    const int blocks = (B + 3) / 4;         // 4 waves (samples) per 256-thr block
    qsim<<<blocks, 256, 0, stream>>>(x, w, out, B);
}

// Round 2
// 104.121 us; speedup vs baseline: 1.2387x; 1.2387x over previous
//
#include <hip/hip_runtime.h>

// 8-qubit statevector sim, one sample per wave64, 4 amps/lane.
// Amp index i = (lane<<2)|j ; amp bits 0..1 = j bits (qubits 7,6),
// amp bits 2..7 = lane bits 0..5 (qubits 5..0). Qubit q <-> amp bit 7-q.
//
// CNOT chains are DEFERRED: chain C = prefix-xor L_C on index bits.
// Layer-l gates are conjugated by C^l: gate on qubit q pairs i with i^m,
// m = L^{-l} e_q (components d with C(l,d) odd, i.e. (l&d)==d), selector
// s = parity(i & r), r = row q of L^l (offsets d with C(d+l-1,l-1) odd).
// Measurement: z_q sign = parity(i & row_q(L^4)) -> qubits {q, q-4}.

#define NL 4
#define NGATES 32

// ---- compile-time GF(2) masks (Lucas: C(n,k) odd iff (n&k)==k) ----
constexpr bool selon(int l, int d) {
    return (l == 0) ? (d == 0) : (((d + l - 1) & (l - 1)) == (l - 1));
}
constexpr int pairmask_lane(int l, int q) {
    int m = 0;
    for (int d = 0; q + d <= 7; ++d)
        if ((l & d) == d) { int qq = q + d; if (qq <= 5) m |= 1 << (5 - qq); }
    return m;
}
constexpr int pairmask_j(int l, int q) {
    int m = 0;
    for (int d = 0; q + d <= 7; ++d)
        if ((l & d) == d) { int qq = q + d; if (qq == 6) m |= 2; else if (qq == 7) m |= 1; }
    return m;
}
constexpr int selmask_lane(int l, int q) {
    int m = 0;
    for (int d = 0; d <= q; ++d)
        if (selon(l, d)) { int k = q - d; if (k <= 5) m |= 1 << (5 - k); }
    return m;
}
constexpr int selmask_j(int l, int q) {
    int m = 0;
    for (int d = 0; d <= q; ++d)
        if (selon(l, d)) { int k = q - d; if (k == 6) m |= 2; else if (k == 7) m |= 1; }
    return m;
}

// xor-shuffle: immediate ds_swizzle for mask<32 (no addr VALU), bpermute for 32+
template<int M>
__device__ __forceinline__ float shx(float v) {
    if constexpr (M == 0) {
        return v;
    } else if constexpr (M < 32) {
        return __int_as_float(__builtin_amdgcn_ds_swizzle(__float_as_int(v), (M << 10) | 0x1F));
    } else {
        return __shfl_xor(v, M, 64);
    }
}

template<int LM, int JM, int SLM, int SJM>
__device__ __forceinline__ void apply_gate(float ar[4], float ai[4], int lane,
                                           const float* __restrict__ g)
{
    const bool pl = (SLM == 0) ? false : (bool)(__builtin_popcount(lane & SLM) & 1);
    const float g0 = g[0], g1 = g[1], g2 = g[2], g3 = g[3];
    const float g4 = g[4], g5 = g[5], g6 = g[6], g7 = g[7];
    float nr[4], ni[4];
    #pragma unroll
    for (int j = 0; j < 4; ++j) {
        const bool flip = (__builtin_popcount(j & SJM) & 1) != 0;
        const bool s = pl != flip;
        const float c0r = s ? g6 : g0, c0i = s ? g7 : g1;   // diag coeff
        const float c1r = s ? g4 : g2, c1i = s ? g5 : g3;   // partner coeff
        const float br = shx<LM>(ar[j ^ JM]);
        const float bi = shx<LM>(ai[j ^ JM]);
        nr[j] = c0r * ar[j] - c0i * ai[j] + c1r * br - c1i * bi;
        ni[j] = c0r * ai[j] + c0i * ar[j] + c1r * bi + c1i * br;
    }
    #pragma unroll
    for (int j = 0; j < 4; ++j) { ar[j] = nr[j]; ai[j] = ni[j]; }
}

#define GATE(L, Q) apply_gate<pairmask_lane(L,Q), pairmask_j(L,Q), \
                              selmask_lane(L,Q), selmask_j(L,Q)>(ar, ai, lane, gsh[(L)*8+(Q)])
#define LAYER(L) GATE(L,0); GATE(L,1); GATE(L,2); GATE(L,3); \
                 GATE(L,4); GATE(L,5); GATE(L,6); GATE(L,7);

__global__ __launch_bounds__(256) void qsim(const float* __restrict__ x,
                                            const float* __restrict__ w,
                                            float* __restrict__ out, int B)
{
    __shared__ float gsh[NGATES][8];  // u00r,u00i,u01r,u01i,u10r,u10i,u11r,u11i

    const int tid = threadIdx.x;
    if (tid < NGATES) {
        float hx = 0.5f * w[tid*3+0];
        float hy = 0.5f * w[tid*3+1];
        float hz = 0.5f * w[tid*3+2];
        float cx = cosf(hx), sx = sinf(hx);
        float cy = cosf(hy), sy = sinf(hy);
        float cz = cosf(hz), sz = sinf(hz);
        // M = RY*RX
        float m00r = cy*cx,  m00i =  sy*sx;
        float m01r = -sy*cx, m01i = -cy*sx;
        float m10r = sy*cx,  m10i = -cy*sx;
        float m11r = cy*cx,  m11i = -sy*sx;
        // U = RZ*M: row0 *= (cz - i sz), row1 *= (cz + i sz)
        gsh[tid][0] = cz*m00r + sz*m00i;
        gsh[tid][1] = cz*m00i - sz*m00r;
        gsh[tid][2] = cz*m01r + sz*m01i;
        gsh[tid][3] = cz*m01i - sz*m01r;
        gsh[tid][4] = cz*m10r - sz*m10i;
        gsh[tid][5] = cz*m10i + sz*m10r;
        gsh[tid][6] = cz*m11r - sz*m11i;
        gsh[tid][7] = cz*m11i + sz*m11r;
    }
    __syncthreads();

    const int lane = tid & 63;
    const int wv   = tid >> 6;
    const int sample = blockIdx.x * 4 + wv;
    if (sample >= B) return;

    // ---- encoding: product state amp(i) = prod_q (bit_{7-q}(i) ? sin : cos)(x_q/2)
    const float4* xp = (const float4*)(x + sample * 8);
    float4 xa = xp[0], xb = xp[1];
    float xs[8] = {xa.x, xa.y, xa.z, xa.w, xb.x, xb.y, xb.z, xb.w};
    float cq[8], sq[8];
    #pragma unroll
    for (int q = 0; q < 8; ++q) {
        float h = 0.5f * xs[q];
        __sincosf(h, &sq[q], &cq[q]);
    }
    float lp = 1.f;
    #pragma unroll
    for (int k = 0; k < 6; ++k)
        lp *= ((lane >> k) & 1) ? sq[5 - k] : cq[5 - k];

    float ar[4], ai[4];
    ar[0] = lp * cq[6] * cq[7];
    ar[1] = lp * cq[6] * sq[7];
    ar[2] = lp * sq[6] * cq[7];
    ar[3] = lp * sq[6] * sq[7];
    ai[0] = ai[1] = ai[2] = ai[3] = 0.f;

    // ---- 4 layers of fused RZ*RY*RX gates, CNOTs deferred into masks ----
    LAYER(0)
    LAYER(1)
    LAYER(2)
    LAYER(3)

    // ---- measurement: z_q sign mask = qubits {q, q-4} of L^4 ----
    float p0 = ar[0]*ar[0] + ai[0]*ai[0];
    float p1 = ar[1]*ar[1] + ai[1]*ai[1];
    float p2 = ar[2]*ar[2] + ai[2]*ai[2];
    float p3 = ar[3]*ar[3] + ai[3]*ai[3];
    float P  = p0 + p1 + p2 + p3;

    float v[8];
    v[0] = (lane & 32) ? -P : P;                       // qubit0 -> lane b5
    v[1] = (lane & 16) ? -P : P;                       // qubit1 -> lane b4
    v[2] = (lane &  8) ? -P : P;                       // qubit2 -> lane b3
    v[3] = (lane &  4) ? -P : P;                       // qubit3 -> lane b2
    v[4] = (__builtin_popcount(lane & 34) & 1) ? -P : P;  // qubits {4,0} -> b1^b5
    v[5] = (__builtin_popcount(lane & 17) & 1) ? -P : P;  // qubits {5,1} -> b0^b4
    float b6 = p0 + p1 - p2 - p3;                      // qubit6 -> j bit1
    v[6] = (lane & 8) ? -b6 : b6;                      //   ^ qubit2 -> lane b3
    float b7 = p0 - p1 + p2 - p3;                      // qubit7 -> j bit0
    v[7] = (lane & 4) ? -b7 : b7;                      //   ^ qubit3 -> lane b2

    #pragma unroll
    for (int q = 0; q < 8; ++q) v[q] += shx<1>(v[q]);
    #pragma unroll
    for (int q = 0; q < 8; ++q) v[q] += shx<2>(v[q]);
    #pragma unroll
    for (int q = 0; q < 8; ++q) v[q] += shx<4>(v[q]);
    #pragma unroll
    for (int q = 0; q < 8; ++q) v[q] += shx<8>(v[q]);
    #pragma unroll
    for (int q = 0; q < 8; ++q) v[q] += shx<16>(v[q]);
    #pragma unroll
    for (int q = 0; q < 8; ++q) v[q] += shx<32>(v[q]);

    if (lane == 0) {
        float4* op = (float4*)(out + sample * 8);
        op[0] = make_float4(v[0], v[1], v[2], v[3]);
        op[1] = make_float4(v[4], v[5], v[6], v[7]);
    }
}

extern "C" void kernel_launch(void* const* d_in, const int* in_sizes, int n_in,
                              void* d_out, int out_size, void* d_ws, size_t ws_size,
                              hipStream_t stream) {
    const float* x = (const float*)d_in[0];
    const float* w = (const float*)d_in[1];
    float* out = (float*)d_out;
    const int B = in_sizes[0] / 8;          // 16384 samples
    const int blocks = (B + 3) / 4;         // 4 waves (samples) per 256-thr block
    qsim<<<blocks, 256, 0, stream>>>(x, w, out, B);
}

// Round 3
// 78.727 us; speedup vs baseline: 1.6383x; 1.3226x over previous
//
#include <hip/hip_runtime.h>

// 8-qubit statevector sim. 4 samples per wave64: 16 lanes/sample, 16 amps/lane.
// Amp index i (8 bits): qubit q<=3 -> lane bit (3-q); qubit q>=4 -> reg bit (7-q).
// CNOT chains deferred into gate conjugation masks (validated in R1):
//   layer-l gate on qubit q pairs i with i^m, m = L^{-l} e_q  (components d, (l&d)==d)
//   row selector s = parity(i & row_q(L^l))                    (offsets d, selon(l,d))
// Fused U = RZ*RY*RX has u11 = conj(u00), u10 = -conj(u01)  =>  row selection is
// just sign flips on Im(u00) and Re(u01), applied via xor 0x80000000.

#define NGATES 32

constexpr bool selon(int l, int d) {
    return (l == 0) ? (d == 0) : (((d + l - 1) & (l - 1)) == (l - 1));
}
// pair mask, lane part (qubits 0..3 -> lane bit 3-q)
constexpr int lm_of(int l, int q) {
    int m = 0;
    for (int d = 0; q + d <= 7; ++d)
        if ((l & d) == d) { int qq = q + d; if (qq <= 3) m |= 1 << (3 - qq); }
    return m;
}
// pair mask, register part (qubits 4..7 -> reg bit 7-q)
constexpr int rm_of(int l, int q) {
    int m = 0;
    for (int d = 0; q + d <= 7; ++d)
        if ((l & d) == d) { int qq = q + d; if (qq >= 4) m |= 1 << (7 - qq); }
    return m;
}
// selector mask, lane part
constexpr int slm_of(int l, int q) {
    int m = 0;
    for (int d = 0; d <= q; ++d)
        if (selon(l, d)) { int k = q - d; if (k <= 3) m |= 1 << (3 - k); }
    return m;
}
// selector mask, register part
constexpr int srm_of(int l, int q) {
    int m = 0;
    for (int d = 0; d <= q; ++d)
        if (selon(l, d)) { int k = q - d; if (k >= 4) m |= 1 << (7 - k); }
    return m;
}

__device__ __forceinline__ float xsgn(float f, unsigned m) {
    return __int_as_float(__float_as_int(f) ^ (int)m);
}

// xor-lane shuffle, mask 1..15: immediate ds_swizzle (stays within 16-lane group)
template<int M>
__device__ __forceinline__ float shx(float v) {
    return __int_as_float(__builtin_amdgcn_ds_swizzle(__float_as_int(v), (M << 10) | 0x1F));
}

template<int LM, int RM, int SLM, int SRM>
__device__ __forceinline__ void apply_gate(float ar[16], float ai[16], int lane,
                                           const float4 g)  // u00r,u00i,u01r,u01i
{
    unsigned sm = 0;
    if constexpr (SLM != 0)
        sm = (unsigned)((__builtin_popcount(lane & SLM) & 1) << 31);
    const float c0r = g.x, c1i = g.w;
    const float c0i0 = xsgn(g.y, sm);
    const float c1r0 = xsgn(g.z, sm);
    const float c0i1 = xsgn(g.y, sm ^ 0x80000000u);
    const float c1r1 = xsgn(g.z, sm ^ 0x80000000u);

    if constexpr (RM == 0) {
        // pure cross-lane: each r independent, partner = swizzled self-register
        #pragma unroll
        for (int r = 0; r < 16; ++r) {
            const bool c1 = (__builtin_popcount(r & SRM) & 1) != 0;
            const float c0i = c1 ? c0i1 : c0i0;
            const float c1r = c1 ? c1r1 : c1r0;
            const float br = shx<LM>(ar[r]);
            const float bi = shx<LM>(ai[r]);
            const float nr = c0r*ar[r] - c0i*ai[r] + c1r*br - c1i*bi;
            const float ni = c0r*ai[r] + c0i*ar[r] + c1r*bi + c1i*br;
            ar[r] = nr; ai[r] = ni;
        }
    } else {
        // register pairs {r, r^RM}; fetch olds (swizzled if LM!=0), update both
        #pragma unroll
        for (int r = 0; r < 16; ++r) {
            const int p = r ^ RM;
            if (p < r) continue;
            float br_r, bi_r, br_p, bi_p;
            if constexpr (LM != 0) {
                br_r = shx<LM>(ar[p]); bi_r = shx<LM>(ai[p]);
                br_p = shx<LM>(ar[r]); bi_p = shx<LM>(ai[r]);
            } else {
                br_r = ar[p]; bi_r = ai[p];
                br_p = ar[r]; bi_p = ai[r];
            }
            const bool cr = (__builtin_popcount(r & SRM) & 1) != 0;
            const bool cp = (__builtin_popcount(p & SRM) & 1) != 0;
            const float c0i_r = cr ? c0i1 : c0i0, c1r_r = cr ? c1r1 : c1r0;
            const float c0i_p = cp ? c0i1 : c0i0, c1r_p = cp ? c1r1 : c1r0;
            const float nr_r = c0r*ar[r] - c0i_r*ai[r] + c1r_r*br_r - c1i*bi_r;
            const float ni_r = c0r*ai[r] + c0i_r*ar[r] + c1r_r*bi_r + c1i*br_r;
            const float nr_p = c0r*ar[p] - c0i_p*ai[p] + c1r_p*br_p - c1i*bi_p;
            const float ni_p = c0r*ai[p] + c0i_p*ar[p] + c1r_p*bi_p + c1i*br_p;
            ar[r] = nr_r; ai[r] = ni_r;
            ar[p] = nr_p; ai[p] = ni_p;
        }
    }
}

#define GATE(L, Q) apply_gate<lm_of(L,Q), rm_of(L,Q), slm_of(L,Q), srm_of(L,Q)>( \
                       ar, ai, lane, gsh4[(L)*8+(Q)])
#define LAYER(L) GATE(L,0); GATE(L,1); GATE(L,2); GATE(L,3); \
                 GATE(L,4); GATE(L,5); GATE(L,6); GATE(L,7);

__global__ __launch_bounds__(256, 4) void qsim(const float* __restrict__ x,
                                               const float* __restrict__ w,
                                               float* __restrict__ out, int B)
{
    __shared__ float4 gsh4[NGATES];  // u00r,u00i,u01r,u01i (row1 = conj structure)

    const int tid = threadIdx.x;
    if (tid < NGATES) {
        float hx = 0.5f * w[tid*3+0];
        float hy = 0.5f * w[tid*3+1];
        float hz = 0.5f * w[tid*3+2];
        float cx = cosf(hx), sx = sinf(hx);
        float cy = cosf(hy), sy = sinf(hy);
        float cz = cosf(hz), sz = sinf(hz);
        // M = RY*RX ; U = RZ*M (row0 only; u11=conj(u00), u10=-conj(u01))
        float m00r = cy*cx,  m00i =  sy*sx;
        float m01r = -sy*cx, m01i = -cy*sx;
        gsh4[tid] = make_float4(cz*m00r + sz*m00i,
                                cz*m00i - sz*m00r,
                                cz*m01r + sz*m01i,
                                cz*m01i - sz*m01r);
    }
    __syncthreads();

    const int lane = tid & 63;
    const int il   = lane & 15;                 // in-sample lane index (amp bits 7:4)
    const int sample = blockIdx.x * 16 + (tid >> 4);
    if (sample >= B) return;

    // ---- encoding: product state ----
    const float4* xp = (const float4*)(x + sample * 8);
    float4 xa = xp[0], xb = xp[1];
    float xs[8] = {xa.x, xa.y, xa.z, xa.w, xb.x, xb.y, xb.z, xb.w};
    float cq[8], sq[8];
    #pragma unroll
    for (int q = 0; q < 8; ++q) {
        float h = 0.5f * xs[q];
        __sincosf(h, &sq[q], &cq[q]);
    }
    // lane product, qubits 0..3 (qubit q -> lane bit 3-q)
    float lp = ((il & 8) ? sq[0] : cq[0]);
    lp      *= ((il & 4) ? sq[1] : cq[1]);
    lp      *= ((il & 2) ? sq[2] : cq[2]);
    lp      *= ((il & 1) ? sq[3] : cq[3]);
    // register tree, qubits 4..7 (reg bit3=q4, b2=q5, b1=q6, b0=q7)
    float t67[4] = {cq[6]*cq[7], cq[6]*sq[7], sq[6]*cq[7], sq[6]*sq[7]};
    float a5[2]  = {cq[5], sq[5]};
    float a4[2]  = {cq[4]*lp, sq[4]*lp};
    float ar[16], ai[16];
    #pragma unroll
    for (int r = 0; r < 16; ++r) {
        ar[r] = a4[(r >> 3) & 1] * a5[(r >> 2) & 1] * t67[r & 3];
        ai[r] = 0.f;
    }

    // ---- 4 layers of fused gates (CNOTs deferred) ----
    LAYER(0)
    LAYER(1)
    LAYER(2)
    LAYER(3)

    // ---- measurement ----
    float p[16];
    #pragma unroll
    for (int r = 0; r < 16; ++r) p[r] = ar[r]*ar[r] + ai[r]*ai[r];

    // register-level signed sums: A_k = sum_r (-1)^{bit k of r} p[r]
    float s0[8], d0[8];
    #pragma unroll
    for (int k = 0; k < 8; ++k) { s0[k] = p[2*k] + p[2*k+1]; d0[k] = p[2*k] - p[2*k+1]; }
    float A0 = ((d0[0]+d0[1]) + (d0[2]+d0[3])) + ((d0[4]+d0[5]) + (d0[6]+d0[7]));
    float s1[4], d1[4];
    #pragma unroll
    for (int k = 0; k < 4; ++k) { s1[k] = s0[2*k] + s0[2*k+1]; d1[k] = s0[2*k] - s0[2*k+1]; }
    float A1 = (d1[0]+d1[1]) + (d1[2]+d1[3]);
    float s2[2], d2[2];
    #pragma unroll
    for (int k = 0; k < 2; ++k) { s2[k] = s1[2*k] + s1[2*k+1]; d2[k] = s1[2*k] - s1[2*k+1]; }
    float A2 = d2[0] + d2[1];
    float A3 = s2[0] - s2[1];
    float P  = s2[0] + s2[1];

    // per-lane sign bitmasks for lane bits
    const unsigned sg1 = (unsigned)(il & 1) << 31;
    const unsigned sg2 = (unsigned)(il & 2) << 30;
    const unsigned sg4 = (unsigned)(il & 4) << 29;
    const unsigned sg8 = (unsigned)(il & 8) << 28;

    // 4-stage WHT of P over the 16-lane group: lane j holds sum_i (-1)^{i.j} P_i
    float wP = P;
    { float t = shx<1>(wP); wP = t + xsgn(wP, sg1); }
    { float t = shx<2>(wP); wP = t + xsgn(wP, sg2); }
    { float t = shx<4>(wP); wP = t + xsgn(wP, sg4); }
    { float t = shx<8>(wP); wP = t + xsgn(wP, sg8); }
    // v0 at il=8, v1 at il=4, v2 at il=2, v3 at il=1

    // signed lane sums for v4..v7 (sign = one lane bit), result in all lanes
    float a3 = xsgn(A3, sg8);
    a3 += shx<1>(a3); a3 += shx<2>(a3); a3 += shx<4>(a3); a3 += shx<8>(a3);
    float a2 = xsgn(A2, sg4);
    a2 += shx<1>(a2); a2 += shx<2>(a2); a2 += shx<4>(a2); a2 += shx<8>(a2);
    float a1 = xsgn(A1, sg2);
    a1 += shx<1>(a1); a1 += shx<2>(a1); a1 += shx<4>(a1); a1 += shx<8>(a1);
    float a0 = xsgn(A0, sg1);
    a0 += shx<1>(a0); a0 += shx<2>(a0); a0 += shx<4>(a0); a0 += shx<8>(a0);

    float* op = out + sample * 8;
    if (il == 8)      { op[0] = wP; op[4] = a3; }
    else if (il == 4) { op[1] = wP; op[5] = a2; }
    else if (il == 2) { op[2] = wP; op[6] = a1; }
    else if (il == 1) { op[3] = wP; op[7] = a0; }
}

extern "C" void kernel_launch(void* const* d_in, const int* in_sizes, int n_in,
                              void* d_out, int out_size, void* d_ws, size_t ws_size,
                              hipStream_t stream) {
    const float* x = (const float*)d_in[0];
    const float* w = (const float*)d_in[1];
    float* out = (float*)d_out;
    const int B = in_sizes[0] / 8;           // 16384 samples
    const int blocks = (B + 15) / 16;        // 16 samples per 256-thread block
    qsim<<<blocks, 256, 0, stream>>>(x, w, out, B);
}